// Round 6
// baseline (1132.859 us; speedup 1.0000x reference)
//
#include <hip/hip_runtime.h>
#include <stdint.h>

// ---------------------------------------------------------------------------
// FrameSoftAttention: out = softmax((q Wq^T)(k Wk^T)^T / 16) (v Wv^T)
// B=128, I=J=1024, D_IN=D_INNER=256, fp32 in/out, bf16 MFMA compute.
// v7: drop LDS staging entirely (Common-mistake #7: K/V/W are L2-resident;
//     staging them was pure sync overhead). All MFMA fragments load
//     global->VGPR directly; compiler pipelines across unrolled loops.
//     attn: LDS = P exchange only; 2 __syncthreads per jt (16 total,
//     was 192 barrier+vmcnt events). proj: zero main-loop barriers.
// v6: depth-2 counted-vmcnt ring (attn 340->280). v5: 512-thr blocks.
// v4: no min-occupancy bound (spill!). v3: V transpose-in-LDS.
// ---------------------------------------------------------------------------

typedef __attribute__((ext_vector_type(4))) float f32x4;
typedef __attribute__((ext_vector_type(8))) short bf16x8;
typedef __attribute__((ext_vector_type(4))) uint32_t u32x4;
typedef __attribute__((ext_vector_type(4))) short s16x4;

#define MFMA(a, b, c) __builtin_amdgcn_mfma_f32_16x16x32_bf16(a, b, c, 0, 0, 0)

__device__ __forceinline__ short f2bf_rne(float f) {
  uint32_t u = __builtin_bit_cast(uint32_t, f);
  u += 0x7FFFu + ((u >> 16) & 1u);
  return (short)(u >> 16);
}

// two fp32 -> packed bf16 pair by truncation (cheap; bias inside 2% budget)
__device__ __forceinline__ uint32_t pack2(float lo, float hi) {
  uint32_t a = __builtin_bit_cast(uint32_t, lo);
  uint32_t b = __builtin_bit_cast(uint32_t, hi);
  return (a >> 16) | (b & 0xFFFF0000u);
}

// ---------------------------------------------------------------------------
// W fp32 [256][256] -> bf16 row-major, all three mats. 768KB read, ~5us.
// ---------------------------------------------------------------------------
__global__ __launch_bounds__(256)
void wconv_kernel(const float* __restrict__ wq, const float* __restrict__ wk,
                  const float* __restrict__ wv, short* __restrict__ wbf) {
  const int mat = blockIdx.y;
  const float* w = (mat == 0) ? wq : (mat == 1) ? wk : wv;
  const int i = (blockIdx.x * 256 + threadIdx.x) * 4;
  f32x4 v = *(const f32x4*)(w + i);
  s16x4 o = {f2bf_rne(v.x), f2bf_rne(v.y), f2bf_rne(v.z), f2bf_rne(v.w)};
  *(s16x4*)(wbf + (size_t)mat * 65536 + i) = o;
}

// ---------------------------------------------------------------------------
// Projection: Y[m,e] = sum_d X[m,d] * W[e,d]; M=131072, N=K=256.
// One block = 128 rows x FULL 256 cols, 512 threads, 8 waves at 64x64.
// All fragments direct global->reg (X from HBM via L1/L2-dedup'd 128B
// segments; W is 128KB L2-resident). No main-loop LDS, no barriers.
// ---------------------------------------------------------------------------
__global__ __launch_bounds__(512)
void proj_kernel(const float* __restrict__ xq, const float* __restrict__ xk,
                 const float* __restrict__ xv, const short* __restrict__ wbf,
                 short* __restrict__ qh, short* __restrict__ kh,
                 short* __restrict__ vt) {
  __shared__ __align__(16) short ldst[128 * 136];   // epilogue only (34.8KB)

  const int mat = blockIdx.y;
  const float* x = (mat == 0) ? xq : (mat == 1) ? xk : xv;
  const short* w = wbf + (size_t)mat * 65536;

  const int tile_m = blockIdx.x * 128;
  const int t = threadIdx.x;
  const int lane = t & 63, wid = t >> 6;        // wid in [0,8)
  const int wm = (wid & 1) * 64, wn = (wid >> 1) * 64;
  const int lr = lane & 15, lq = lane >> 4;

  f32x4 acc[4][4];
#pragma unroll
  for (int i = 0; i < 4; ++i)
#pragma unroll
    for (int j = 0; j < 4; ++j) acc[i][j] = (f32x4)0.0f;

  // per-lane fragment base pointers (row picked by lr, k-slot by lq)
  const float* xb = x + (size_t)(tile_m + wm + lr) * 256 + lq * 8;
  const short* wb = w + (size_t)(wn + lr) * 256 + lq * 8;

#pragma unroll
  for (int kk = 0; kk < 8; ++kk) {
    bf16x8 af[4], bf[4];
#pragma unroll
    for (int mi = 0; mi < 4; ++mi) {
      const float* p = xb + (size_t)mi * 16 * 256 + kk * 32;
      f32x4 lo = *(const f32x4*)p;
      f32x4 hi = *(const f32x4*)(p + 4);
      u32x4 pk = {pack2(lo.x, lo.y), pack2(lo.z, lo.w), pack2(hi.x, hi.y),
                  pack2(hi.z, hi.w)};
      af[mi] = __builtin_bit_cast(bf16x8, pk);
    }
#pragma unroll
    for (int ni = 0; ni < 4; ++ni)
      bf[ni] = *(const bf16x8*)(wb + (size_t)ni * 16 * 256 + kk * 32);
    __builtin_amdgcn_s_setprio(1);
#pragma unroll
    for (int mi = 0; mi < 4; ++mi)
#pragma unroll
      for (int ni = 0; ni < 4; ++ni)
        acc[mi][ni] = MFMA(af[mi], bf[ni], acc[mi][ni]);
    __builtin_amdgcn_s_setprio(0);
  }
  __syncthreads();   // (paranoia; ldst unwritten yet) keep waves together

  // Epilogue: two 128-col passes through LDS -> coalesced 16B stores.
  // mat==2 (V): transpose in LDS (ldst[n][m]) so LDS rows are e-rows,
  // matching the vt[e][j] store layout.
  const float scale = (mat == 0) ? 0.0625f : 1.0f;
  const int bb = tile_m >> 10, j0 = tile_m & 1023;
#pragma unroll
  for (int p = 0; p < 2; ++p) {
    if (((wid >> 1) >> 1) == p) {
#pragma unroll
      for (int mi = 0; mi < 4; ++mi)
#pragma unroll
        for (int ni = 0; ni < 4; ++ni)
#pragma unroll
          for (int r = 0; r < 4; ++r) {
            int m = wm + mi * 16 + lq * 4 + r;            // C/D row
            int n = ((wid >> 1) & 1) * 64 + ni * 16 + lr; // col local to pass
            short bv = f2bf_rne(acc[mi][ni][r] * scale);
            if (mat < 2) ldst[m * 136 + n] = bv;
            else         ldst[n * 136 + m] = bv;
          }
    }
    __syncthreads();
#pragma unroll
    for (int q = 0; q < 4; ++q) {
      int idx = q * 512 + t;
      int row = idx >> 4;
      int col8 = (idx & 15) * 8;
      bf16x8 vdat = *(const bf16x8*)(ldst + row * 136 + col8);
      short* dst;
      if (mat < 2) {
        short* o = (mat == 0) ? qh : kh;
        dst = o + (size_t)(tile_m + row) * 256 + p * 128 + col8;
      } else {
        dst = vt + ((size_t)(bb * 256 + p * 128 + row)) * 1024 + j0 + col8;
      }
      *(bf16x8*)dst = vdat;
    }
    __syncthreads();
  }
}

// ---------------------------------------------------------------------------
// Attention: one block per (batch, 128-row q tile), 512 threads (8 waves).
// grid=(128, 8) so all q-tiles of batch b hash to XCD b%8 (kh/vt L2 reuse).
// Q/K/V fragments load global->reg directly (L2-hot: K/V shared by the 8
// same-XCD blocks, Q re-read per jt). LDS holds only P; two __syncthreads
// per j-tile: (a) jt top = previous PV done before P overwrite, (b) after
// P write = publish to sibling cg wave.
// ---------------------------------------------------------------------------
__global__ __launch_bounds__(512)
void attn_kernel(const short* __restrict__ qh, const short* __restrict__ kh,
                 const short* __restrict__ vt, float* __restrict__ out) {
  __shared__ __align__(16) short ldsP[128 * 136];   // P, bf16 (34.8KB)

  const int b = blockIdx.x;
  const int i0 = blockIdx.y * 128;
  const int t = threadIdx.x;
  const int lane = t & 63, wid = t >> 6;  // wid in [0,8)
  const int rg = wid >> 1, cg = wid & 1;  // rows rg*32, QK cols cg*64, PV d cg*128
  const int lr = lane & 15, lq = lane >> 4;
  const size_t bq = (size_t)b * 262144;

  f32x4 oacc[2][8];
#pragma unroll
  for (int i = 0; i < 2; ++i)
#pragma unroll
    for (int j = 0; j < 8; ++j) oacc[i][j] = (f32x4)0.0f;
  float lsum[8];
#pragma unroll
  for (int i = 0; i < 8; ++i) lsum[i] = 0.0f;

  // per-lane fragment base pointers
  const short* qb = qh + bq + (size_t)(i0 + rg * 32 + lr) * 256 + lq * 8;
  const short* kb = kh + bq + (size_t)(cg * 64 + lr) * 256 + lq * 8;  // + j0*256
  const short* vb = vt + bq + (size_t)(cg * 128 + lr) * 1024 + lq * 8; // + j0+kc*32
  const f32x4* p4 = (const f32x4*)ldsP;

  for (int jt = 0; jt < 8; ++jt) {
    const int j0 = jt * 128;
    __syncthreads();   // all waves done with previous jt's P

    f32x4 sacc[2][4];
#pragma unroll
    for (int i = 0; i < 2; ++i)
#pragma unroll
      for (int j = 0; j < 4; ++j) sacc[i][j] = (f32x4)0.0f;

    // ---- S = Q K^T over d (8 chunks of 32), fragments from global ----
    const short* kbj = kb + (size_t)j0 * 256;
#pragma unroll
    for (int kk = 0; kk < 8; ++kk) {
      bf16x8 aq[2], bk[4];
#pragma unroll
      for (int mi = 0; mi < 2; ++mi)
        aq[mi] = *(const bf16x8*)(qb + (size_t)mi * 16 * 256 + kk * 32);
#pragma unroll
      for (int ni = 0; ni < 4; ++ni)
        bk[ni] = *(const bf16x8*)(kbj + (size_t)ni * 16 * 256 + kk * 32);
      __builtin_amdgcn_s_setprio(1);
#pragma unroll
      for (int mi = 0; mi < 2; ++mi)
#pragma unroll
        for (int ni = 0; ni < 4; ++ni)
          sacc[mi][ni] = MFMA(aq[mi], bk[ni], sacc[mi][ni]);
      __builtin_amdgcn_s_setprio(0);
    }

    // ---- P = exp(S), row partial sums, P -> LDS (bf16) ----
    float prt[8];
#pragma unroll
    for (int i = 0; i < 8; ++i) prt[i] = 0.0f;
#pragma unroll
    for (int mi = 0; mi < 2; ++mi)
#pragma unroll
      for (int ni = 0; ni < 4; ++ni)
#pragma unroll
        for (int r = 0; r < 4; ++r) {
          float e = __expf(sacc[mi][ni][r]);
          prt[mi * 4 + r] += e;
          int m = rg * 32 + mi * 16 + lq * 4 + r;
          int jc = cg * 64 + ni * 16 + lr;
          ldsP[m * 136 + jc] = f2bf_rne(e);
        }
#pragma unroll
    for (int v = 0; v < 8; ++v) {
      float p = prt[v];
      p += __shfl_xor(p, 1, 64);
      p += __shfl_xor(p, 2, 64);
      p += __shfl_xor(p, 4, 64);
      p += __shfl_xor(p, 8, 64);
      lsum[v] += p;
    }
    __syncthreads();   // publish P to the sibling cg wave

    // ---- O += P V (4 kc chunks of 32 keys); V fragments from global ----
#pragma unroll
    for (int kc = 0; kc < 4; ++kc) {
      bf16x8 pf[2], vf[8];
#pragma unroll
      for (int mi = 0; mi < 2; ++mi) {
        int m = rg * 32 + mi * 16 + lr;
        pf[mi] = __builtin_bit_cast(bf16x8, p4[m * 17 + kc * 4 + lq]);
      }
#pragma unroll
      for (int ni = 0; ni < 8; ++ni)
        vf[ni] = *(const bf16x8*)(vb + (size_t)ni * 16 * 1024 + j0 + kc * 32);
      __builtin_amdgcn_s_setprio(1);
#pragma unroll
      for (int mi = 0; mi < 2; ++mi)
#pragma unroll
        for (int ni = 0; ni < 8; ++ni)
          oacc[mi][ni] = MFMA(pf[mi], vf[ni], oacc[mi][ni]);
      __builtin_amdgcn_s_setprio(0);
    }
  }
  __syncthreads();   // all PV reads of ldsP done before lscr aliases it

  // ---- epilogue: combine denominators across wave pairs, normalize ----
  float* lscr = (float*)ldsP;
  if (lr == 0) {
#pragma unroll
    for (int mi = 0; mi < 2; ++mi)
#pragma unroll
      for (int r = 0; r < 4; ++r)
        lscr[wid * 32 + mi * 16 + lq * 4 + r] = lsum[mi * 4 + r];
  }
  __syncthreads();
  float inv[8];
#pragma unroll
  for (int mi = 0; mi < 2; ++mi)
#pragma unroll
    for (int r = 0; r < 4; ++r) {
      float tot = lsum[mi * 4 + r] + lscr[(wid ^ 1) * 32 + mi * 16 + lq * 4 + r];
      inv[mi * 4 + r] = 1.0f / tot;
    }
#pragma unroll
  for (int mi = 0; mi < 2; ++mi)
#pragma unroll
    for (int ni = 0; ni < 8; ++ni)
#pragma unroll
      for (int r = 0; r < 4; ++r) {
        int i = i0 + rg * 32 + mi * 16 + lq * 4 + r;
        int d = cg * 128 + ni * 16 + lr;
        out[bq + (size_t)i * 256 + d] = oacc[mi][ni][r] * inv[mi * 4 + r];
      }
}

// ---------------------------------------------------------------------------
extern "C" void kernel_launch(void* const* d_in, const int* in_sizes, int n_in,
                              void* d_out, int out_size, void* d_ws,
                              size_t ws_size, hipStream_t stream) {
  (void)in_sizes; (void)n_in; (void)out_size; (void)ws_size;
  const float* q  = (const float*)d_in[0];
  const float* k  = (const float*)d_in[1];
  const float* v  = (const float*)d_in[2];
  const float* wq = (const float*)d_in[3];
  const float* wk = (const float*)d_in[4];
  const float* wv = (const float*)d_in[5];
  float* out = (float*)d_out;

  // ws layout: qh | kh | vt, each 128*1024*256 bf16 (67.1 MB) -> 201.3 MB
  short* qh = (short*)d_ws;
  short* kh = qh + (size_t)33554432;
  short* vt = kh + (size_t)33554432;
  // W bf16 scratch (384 KB) lives at the head of d_out; d_out is only
  // written by attn_kernel's epilogue, which runs strictly after proj.
  short* wbf = (short*)d_out;

  wconv_kernel<<<dim3(64, 3), dim3(256), 0, stream>>>(wq, wk, wv, wbf);
  proj_kernel<<<dim3(1024, 3), dim3(512), 0, stream>>>(
      q, k, v, wbf, qh, kh, vt);
  attn_kernel<<<dim3(128, 8), dim3(512), 0, stream>>>(qh, kh, vt, out);
}

// Round 7
// 670.263 us; speedup vs baseline: 1.6902x; 1.6902x over previous
//
#include <hip/hip_runtime.h>
#include <stdint.h>

// ---------------------------------------------------------------------------
// FrameSoftAttention: out = softmax((q Wq^T)(k Wk^T)^T / 16) (v Wv^T)
// B=128, I=J=1024, D_IN=D_INNER=256, fp32 in/out, bf16 MFMA compute.
// v8 = v6 + attn: Q held in VGPRs (64/thread, loaded once; kills 64 of 192
//      staging units + 8x Q re-read) + depth-3 counted ring (vmcnt(2),
//      issue u+3 on ring-4: legal, slot (u+3)&3 last read one barrier ago).
//      proj/wconv = v6 verbatim.
// v7 LESSON: per-lane-scattered global fragment loads = 64 cache lines per
//      VMEM instr (~64-cycle issue each) -> attn 541us, Mfma 10%. Direct-
//      to-reg only works when the fragment pattern is coalesced; ours isn't.
// v6: depth-2 counted-vmcnt 8KB-unit ring (attn 280us). v5: 512-thr blocks.
// v4: no min-occupancy bound (spill!). v3: V transpose-in-LDS.
// ---------------------------------------------------------------------------

typedef __attribute__((ext_vector_type(4))) float f32x4;
typedef __attribute__((ext_vector_type(8))) short bf16x8;
typedef __attribute__((ext_vector_type(4))) uint32_t u32x4;
typedef __attribute__((ext_vector_type(4))) short s16x4;

#define MFMA(a, b, c) __builtin_amdgcn_mfma_f32_16x16x32_bf16(a, b, c, 0, 0, 0)

typedef const __attribute__((address_space(1))) uint32_t* gas1_t;
typedef __attribute__((address_space(3))) uint32_t* las3_t;

__device__ __forceinline__ void async16(const void* g, void* l) {
  // 16B direct global->LDS; lands at wave-uniform base + lane*16.
  __builtin_amdgcn_global_load_lds((gas1_t)g, (las3_t)l, 16, 0, 0);
}

__device__ __forceinline__ short f2bf_rne(float f) {
  uint32_t u = __builtin_bit_cast(uint32_t, f);
  u += 0x7FFFu + ((u >> 16) & 1u);
  return (short)(u >> 16);
}

// two fp32 -> packed bf16 pair by truncation (cheap; bias inside 2% budget)
__device__ __forceinline__ uint32_t pack2(float lo, float hi) {
  uint32_t a = __builtin_bit_cast(uint32_t, lo);
  uint32_t b = __builtin_bit_cast(uint32_t, hi);
  return (a >> 16) | (b & 0xFFFF0000u);
}

// Counted-vmcnt unit barrier: wait until <=N of this wave's global_load_lds
// remain in flight, then block barrier. Loads above N stay in flight.
template <int N>
__device__ __forceinline__ void unit_wait() {
  __builtin_amdgcn_sched_barrier(0);
  if constexpr (N == 0)
    asm volatile("s_waitcnt vmcnt(0)" ::: "memory");
  else if constexpr (N == 1)
    asm volatile("s_waitcnt vmcnt(1)" ::: "memory");
  else
    asm volatile("s_waitcnt vmcnt(2)" ::: "memory");
  __builtin_amdgcn_s_barrier();
  __builtin_amdgcn_sched_barrier(0);
}

// ---------------------------------------------------------------------------
// W fp32 [256][256] -> bf16 row-major, all three mats. 768KB read, ~5us.
// ---------------------------------------------------------------------------
__global__ __launch_bounds__(256)
void wconv_kernel(const float* __restrict__ wq, const float* __restrict__ wk,
                  const float* __restrict__ wv, short* __restrict__ wbf) {
  const int mat = blockIdx.y;
  const float* w = (mat == 0) ? wq : (mat == 1) ? wk : wv;
  const int i = (blockIdx.x * 256 + threadIdx.x) * 4;
  f32x4 v = *(const f32x4*)(w + i);
  s16x4 o = {f2bf_rne(v.x), f2bf_rne(v.y), f2bf_rne(v.z), f2bf_rne(v.w)};
  *(s16x4*)(wbf + (size_t)mat * 65536 + i) = o;
}

// ---------------------------------------------------------------------------
// Projection: Y[m,e] = sum_d X[m,d] * W[e,d]; M=131072, N=K=256.
// One block = 128 rows x FULL 256 cols (X read once from HBM), 512 threads.
// 8 waves at 64x64 (acc[4][4]). K-loop: 16 units (X_kk, W_kk alternating),
// 4-ring of 16KB, vmcnt(2) depth-2 pipeline. Compute on W units. (= v6)
// ---------------------------------------------------------------------------
__global__ __launch_bounds__(512)
void proj_kernel(const float* __restrict__ xq, const float* __restrict__ xk,
                 const float* __restrict__ xv, const short* __restrict__ wbf,
                 short* __restrict__ qh, short* __restrict__ kh,
                 short* __restrict__ vt) {
  __shared__ __align__(16) char smem[65536];   // 4 x 16KB ring
  short* ldst = (short*)smem;                  // epilogue alias [128][136]

  const int mat = blockIdx.y;
  const float* x = (mat == 0) ? xq : (mat == 1) ? xk : xv;
  const short* w = wbf + (size_t)mat * 65536;

  const int tile_m = blockIdx.x * 128;
  const int t = threadIdx.x;
  const int lane = t & 63, wid = t >> 6;        // wid in [0,8)
  const int wm = (wid & 1) * 64, wn = (wid >> 1) * 64;
  const int lr = lane & 15, lq = lane >> 4;

  f32x4 acc[4][4];
#pragma unroll
  for (int i = 0; i < 4; ++i)
#pragma unroll
    for (int j = 0; j < 4; ++j) acc[i][j] = (f32x4)0.0f;

  // unit u (0..15): even = X chunk kk=u/2 (128x32 fp32), odd = W chunk
  // (256x32 bf16). Each 16KB, 2 loads/thread, into ring slot u&3.
  auto ISSUE = [&](int u) {
    if (u >= 16) return;
    char* base = smem + (u & 3) * 16384;
    const int k0 = (u >> 1) * 32;
    if ((u & 1) == 0) {
#pragma unroll
      for (int c = 0; c < 2; ++c) {
        int s = c * 512 + t;
        // X slot(r,c8) = (r>>4)*128 + c8*16 + (r&15), c8 in 0..7 (f32x4)
        int rx = ((s >> 7) << 4) | (s & 15);
        int cx = (s >> 4) & 7;
        async16(x + (size_t)(tile_m + rx) * 256 + k0 + cx * 4, base + s * 16);
      }
    } else {
#pragma unroll
      for (int c = 0; c < 2; ++c) {
        int s = c * 512 + t;
        // W slot(r,c8) = (r>>4)*64 + c8*16 + (r&15), c8 in 0..3 (bf16x8)
        int rw = ((s >> 6) << 4) | (s & 15);
        int cw = (s >> 4) & 3;
        async16(w + (size_t)rw * 256 + k0 + cw * 8, base + s * 16);
      }
    }
  };

  ISSUE(0);
  ISSUE(1);
  for (int kk = 0; kk < 8; ++kk) {
    const int u = kk * 2 + 1;                 // W unit index of this chunk
    // X unit (u-1)
    unit_wait<2>();
    ISSUE(u + 1);
    // W unit (u)
    if (kk == 7) unit_wait<0>(); else unit_wait<2>();
    ISSUE(u + 2);
    const f32x4* x4 = (const f32x4*)(smem + ((u - 1) & 3) * 16384);
    const f32x4* w4 = (const f32x4*)(smem + (u & 3) * 16384);
    bf16x8 af[4], bf[4];
#pragma unroll
    for (int mi = 0; mi < 4; ++mi) {
      int row = wm + mi * 16 + lr;
      int sl = ((row >> 4) << 7) + (lq << 5) + (row & 15);
      f32x4 lo = x4[sl], hi = x4[sl + 16];
      u32x4 pk = {pack2(lo.x, lo.y), pack2(lo.z, lo.w), pack2(hi.x, hi.y),
                  pack2(hi.z, hi.w)};
      af[mi] = __builtin_bit_cast(bf16x8, pk);
    }
#pragma unroll
    for (int ni = 0; ni < 4; ++ni) {
      int col = wn + ni * 16 + lr;
      bf[ni] = __builtin_bit_cast(
          bf16x8, w4[((col >> 4) << 6) + (lq << 4) + (col & 15)]);
    }
    __builtin_amdgcn_s_setprio(1);
#pragma unroll
    for (int mi = 0; mi < 4; ++mi)
#pragma unroll
      for (int ni = 0; ni < 4; ++ni)
        acc[mi][ni] = MFMA(af[mi], bf[ni], acc[mi][ni]);
    __builtin_amdgcn_s_setprio(0);
  }
  __syncthreads();   // all waves done computing before ldst aliases the ring

  // Epilogue: two 128-col passes through LDS -> coalesced 16B stores.
  // mat==2 (V): transpose in LDS (ldst[n][m]) so LDS rows are e-rows,
  // matching the vt[e][j] store layout.
  const float scale = (mat == 0) ? 0.0625f : 1.0f;
  const int bb = tile_m >> 10, j0 = tile_m & 1023;
#pragma unroll
  for (int p = 0; p < 2; ++p) {
    if (((wid >> 1) >> 1) == p) {
#pragma unroll
      for (int mi = 0; mi < 4; ++mi)
#pragma unroll
        for (int ni = 0; ni < 4; ++ni)
#pragma unroll
          for (int r = 0; r < 4; ++r) {
            int m = wm + mi * 16 + lq * 4 + r;            // C/D row
            int n = ((wid >> 1) & 1) * 64 + ni * 16 + lr; // col local to pass
            short bv = f2bf_rne(acc[mi][ni][r] * scale);
            if (mat < 2) ldst[m * 136 + n] = bv;
            else         ldst[n * 136 + m] = bv;
          }
    }
    __syncthreads();
#pragma unroll
    for (int q = 0; q < 4; ++q) {
      int idx = q * 512 + t;
      int row = idx >> 4;
      int col8 = (idx & 15) * 8;
      bf16x8 vdat = *(const bf16x8*)(ldst + row * 136 + col8);
      short* dst;
      if (mat < 2) {
        short* o = (mat == 0) ? qh : kh;
        dst = o + (size_t)(tile_m + row) * 256 + p * 128 + col8;
      } else {
        dst = vt + ((size_t)(bb * 256 + p * 128 + row)) * 1024 + j0 + col8;
      }
      *(bf16x8*)dst = vdat;
    }
    __syncthreads();
  }
}

// ---------------------------------------------------------------------------
// Attention: one block per (batch, 128-row q tile), 512 threads (8 waves).
// grid=(128, 8) so all q-tiles of batch b hash to XCD b%8 (kh/vt L2 reuse).
// Q lives in VGPRs (16 bf16x8/thread, loaded once). Unit stream per j-tile
// (16 x 8KB units, 1 load/thread): K0..K7 | Vlo0 Vhi0 .. Vlo3 Vhi3.
// Ring-4 of 8KB, depth-3 in flight (vmcnt(2), issue u+3).
// ---------------------------------------------------------------------------
__global__ __launch_bounds__(512)
void attn_kernel(const short* __restrict__ qh, const short* __restrict__ kh,
                 const short* __restrict__ vt, float* __restrict__ out) {
  __shared__ __align__(16) char smem[32768 + 34816];
  short* ldsS = (short*)smem;             // 4 x 8KB (4096-short) ring
  short* ldsP = (short*)(smem + 32768);   // P [128][136] bf16

  const int b = blockIdx.x;
  const int i0 = blockIdx.y * 128;
  const int t = threadIdx.x;
  const int lane = t & 63, wid = t >> 6;  // wid in [0,8)
  const int rg = wid >> 1, cg = wid & 1;  // rows rg*32, QK cols cg*64, PV d cg*128
  const int lr = lane & 15, lq = lane >> 4;
  const size_t bq = (size_t)b * 262144;

  // ---- Q -> registers (one-time; scattered but amortized over 8 jt) ----
  bf16x8 qreg[2][8];
  {
    const short* qb = qh + bq + (size_t)(i0 + rg * 32 + lr) * 256 + lq * 8;
#pragma unroll
    for (int mi = 0; mi < 2; ++mi)
#pragma unroll
      for (int kk = 0; kk < 8; ++kk)
        qreg[mi][kk] =
            *(const bf16x8*)(qb + (size_t)(mi * 16) * 256 + kk * 32);
  }

  f32x4 oacc[2][8];
#pragma unroll
  for (int i = 0; i < 2; ++i)
#pragma unroll
    for (int j = 0; j < 8; ++j) oacc[i][j] = (f32x4)0.0f;
  float lsum[8];
#pragma unroll
  for (int i = 0; i < 8; ++i) lsum[i] = 0.0f;

  // unit u (0..127): jt = u>>4, r = u&15.
  //  r<8:  K chunk kk=r (128 j-rows x 32 d), k0=r*32.
  //  r>=8: v=r-8; kc=v>>1; half=v&1: vt d-rows [half*128,+128), 32 keys.
  auto ISSUE = [&](int u) {
    if (u >= 128) return;
    short* base = ldsS + (u & 3) * 4096;
    const int jt = u >> 4, r = u & 15;
    const int j0 = jt * 128;
    const int s = t;                       // 512 slots of 16B = 8KB
    if (r < 8) {
      const int k0 = r * 32;
      int rr = ((s >> 6) << 4) | (s & 15);
      int c8 = (s >> 4) & 3;
      async16(kh + bq + (size_t)(j0 + rr) * 256 + k0 + c8 * 8, base + s * 8);
    } else {
      const int v = r - 8;
      const int kc = v >> 1, half = v & 1;
      int d = (half << 7) | ((s >> 6) << 4) | (s & 15);
      int c8 = (s >> 4) & 3;
      async16(vt + bq + (size_t)d * 1024 + j0 + kc * 32 + c8 * 8, base + s * 8);
    }
  };

  ISSUE(0);
  ISSUE(1);
  ISSUE(2);
  int u = 0;

  for (int jt = 0; jt < 8; ++jt) {
    f32x4 sacc[2][4];
#pragma unroll
    for (int i = 0; i < 2; ++i)
#pragma unroll
      for (int j = 0; j < 4; ++j) sacc[i][j] = (f32x4)0.0f;

    // ---- S = Q K^T over d (8 K units; Q from registers) ----
#pragma unroll
    for (int kk = 0; kk < 8; ++kk) {
      unit_wait<2>();                      // K unit u landed
      ISSUE(u + 3);
      const f32x4* k4 = (const f32x4*)(ldsS + (u & 3) * 4096);
      bf16x8 bk[4];
#pragma unroll
      for (int ni = 0; ni < 4; ++ni) {
        int col = cg * 64 + ni * 16 + lr;
        bk[ni] = __builtin_bit_cast(
            bf16x8, k4[((col >> 4) << 6) + (lq << 4) + (col & 15)]);
      }
      __builtin_amdgcn_s_setprio(1);
#pragma unroll
      for (int mi = 0; mi < 2; ++mi)
#pragma unroll
        for (int ni = 0; ni < 4; ++ni)
          sacc[mi][ni] = MFMA(qreg[mi][kk], bk[ni], sacc[mi][ni]);
      __builtin_amdgcn_s_setprio(0);
      ++u;
    }

    // ---- P = exp(S), row partial sums, P -> LDS (bf16) ----
    float prt[8];
#pragma unroll
    for (int i = 0; i < 8; ++i) prt[i] = 0.0f;
#pragma unroll
    for (int mi = 0; mi < 2; ++mi)
#pragma unroll
      for (int ni = 0; ni < 4; ++ni)
#pragma unroll
        for (int r = 0; r < 4; ++r) {
          float e = __expf(sacc[mi][ni][r]);
          prt[mi * 4 + r] += e;
          int m = rg * 32 + mi * 16 + lq * 4 + r;
          int jc = cg * 64 + ni * 16 + lr;
          ldsP[m * 136 + jc] = f2bf_rne(e);
        }
#pragma unroll
    for (int v = 0; v < 8; ++v) {
      float p = prt[v];
      p += __shfl_xor(p, 1, 64);
      p += __shfl_xor(p, 2, 64);
      p += __shfl_xor(p, 4, 64);
      p += __shfl_xor(p, 8, 64);
      lsum[v] += p;
    }
    // P ds_writes retired here; the NEXT unit barrier (Vlo0) publishes them
    // to the sibling wave; first P read is after Vhi0's barrier (one later).
    asm volatile("s_waitcnt lgkmcnt(0)" ::: "memory");

    // ---- O += P V (4 kc chunks; Vlo/Vhi units) ----
    const f32x4* p4 = (const f32x4*)ldsP;
#pragma unroll
    for (int kc = 0; kc < 4; ++kc) {
      // Vlo unit
      if (jt == 7 && kc == 3) unit_wait<1>(); else unit_wait<2>();
      ISSUE(u + 3);
      ++u;
      // Vhi unit
      if (jt == 7 && kc == 3) unit_wait<0>(); else unit_wait<2>();
      ISSUE(u + 3);
      // cg=0 waves read d 0..127 (Vlo, ring u-1); cg=1 read Vhi (ring u).
      const f32x4* v4 =
          (const f32x4*)(ldsS + ((cg ? u : (u - 1)) & 3) * 4096);
      bf16x8 pf[2], vf[8];
#pragma unroll
      for (int mi = 0; mi < 2; ++mi) {
        int m = rg * 32 + mi * 16 + lr;
        pf[mi] = __builtin_bit_cast(bf16x8, p4[m * 17 + kc * 4 + lq]);
      }
#pragma unroll
      for (int ni = 0; ni < 8; ++ni) {
        // local d' = ni*16+lr (0..127) within the wave's half-unit
        vf[ni] = __builtin_bit_cast(bf16x8, v4[ni * 64 + (lq << 4) + lr]);
      }
      __builtin_amdgcn_s_setprio(1);
#pragma unroll
      for (int mi = 0; mi < 2; ++mi)
#pragma unroll
        for (int ni = 0; ni < 8; ++ni)
          oacc[mi][ni] = MFMA(pf[mi], vf[ni], oacc[mi][ni]);
      __builtin_amdgcn_s_setprio(0);
      ++u;
    }
  }
  __syncthreads();   // all PV reads of ldsP done before lscr aliases it

  // ---- epilogue: combine denominators across wave pairs, normalize ----
  float* lscr = (float*)ldsP;
  if (lr == 0) {
#pragma unroll
    for (int mi = 0; mi < 2; ++mi)
#pragma unroll
      for (int r = 0; r < 4; ++r)
        lscr[wid * 32 + mi * 16 + lq * 4 + r] = lsum[mi * 4 + r];
  }
  __syncthreads();
  float inv[8];
#pragma unroll
  for (int mi = 0; mi < 2; ++mi)
#pragma unroll
    for (int r = 0; r < 4; ++r) {
      float tot = lsum[mi * 4 + r] + lscr[(wid ^ 1) * 32 + mi * 16 + lq * 4 + r];
      inv[mi * 4 + r] = 1.0f / tot;
    }
#pragma unroll
  for (int mi = 0; mi < 2; ++mi)
#pragma unroll
    for (int ni = 0; ni < 8; ++ni)
#pragma unroll
      for (int r = 0; r < 4; ++r) {
        int i = i0 + rg * 32 + mi * 16 + lq * 4 + r;
        int d = cg * 128 + ni * 16 + lr;
        out[bq + (size_t)i * 256 + d] = oacc[mi][ni][r] * inv[mi * 4 + r];
      }
}

// ---------------------------------------------------------------------------
extern "C" void kernel_launch(void* const* d_in, const int* in_sizes, int n_in,
                              void* d_out, int out_size, void* d_ws,
                              size_t ws_size, hipStream_t stream) {
  (void)in_sizes; (void)n_in; (void)out_size; (void)ws_size;
  const float* q  = (const float*)d_in[0];
  const float* k  = (const float*)d_in[1];
  const float* v  = (const float*)d_in[2];
  const float* wq = (const float*)d_in[3];
  const float* wk = (const float*)d_in[4];
  const float* wv = (const float*)d_in[5];
  float* out = (float*)d_out;

  // ws layout: qh | kh | vt, each 128*1024*256 bf16 (67.1 MB) -> 201.3 MB
  short* qh = (short*)d_ws;
  short* kh = qh + (size_t)33554432;
  short* vt = kh + (size_t)33554432;
  // W bf16 scratch (384 KB) lives at the head of d_out; d_out is only
  // written by attn_kernel's epilogue, which runs strictly after proj.
  short* wbf = (short*)d_out;

  wconv_kernel<<<dim3(64, 3), dim3(256), 0, stream>>>(wq, wk, wv, wbf);
  proj_kernel<<<dim3(1024, 3), dim3(512), 0, stream>>>(
      q, k, v, wbf, qh, kh, vt);
  attn_kernel<<<dim3(128, 8), dim3(512), 0, stream>>>(qh, kh, vt, out);
}